// Round 1
// baseline (10.517 us; speedup 1.0000x reference)
//
#include <hip/hip_runtime.h>
#include <math.h>

// Problem constants
#define BS     256
#define IMG_H  64
#define IMG_W  64
#define OH     31
#define OW     31
#define NPOS   (OH * OW)          // 961
#define NPATCH (BS * NPOS)        // 246016

// Apply RY(theta) (c=cos(th/2), s=sin(th/2)) on the qubit at bit position `bit`
// of a 16-amplitude real state held in registers.
__device__ __forceinline__ void ry_on(float* st, int bit, float c, float s) {
    const int m = 1 << bit;
#pragma unroll
    for (int i = 0; i < 16; ++i) {
        if (!(i & m)) {
            float a0 = st[i];
            float a1 = st[i | m];
            st[i]     = c * a0 - s * a1;
            st[i | m] = s * a0 + c * a1;
        }
    }
}

// CNOT with control at bit `cb`, target at bit `tb`.
__device__ __forceinline__ void cnot_on(float* st, int cb, int tb) {
    const int cm = 1 << cb, tm = 1 << tb;
#pragma unroll
    for (int i = 0; i < 16; ++i) {
        if ((i & cm) && !(i & tm)) {
            float tmp = st[i];
            st[i] = st[i | tm];
            st[i | tm] = tmp;
        }
    }
}

__global__ __launch_bounds__(256) void encoder_kernel(
    const float* __restrict__ img,     // (256,1,64,64)
    const float* __restrict__ wmps,    // (2,3,2) = 12 floats
    float* __restrict__ out)           // (256,1,961)
{
    // Per-block precompute of the 12 rotation cos/sin (angles/2).
    __shared__ float sc[12], ss[12];
    const int t = threadIdx.x;
    if (t < 12) {
        float th = 0.5f * wmps[t];
        sc[t] = cosf(th);
        ss[t] = sinf(th);
    }
    __syncthreads();

    int idx = blockIdx.x * blockDim.x + t;
    if (idx >= NPATCH) return;

    const int b   = idx / NPOS;
    const int pos = idx - b * NPOS;
    const int oi  = pos / OW;
    const int oj  = pos - oi * OW;

    const float* base = img + ((size_t)b * IMG_H + (size_t)(oi * 2)) * IMG_W + (oj * 2);

    // Load 16-value patch (feature order kh*4+kw), track squared norm.
    float st[16];
    float n2 = 0.0f;
#pragma unroll
    for (int kh = 0; kh < 4; ++kh) {
#pragma unroll
        for (int kw = 0; kw < 4; ++kw) {
            float v = base[kh * IMG_W + kw];
            st[kh * 4 + kw] = v;
            n2 += v * v;
        }
    }

    // norm==0 fallback: reference embeds e0.
    if (n2 <= 0.0f) { st[0] = 1.0f; n2 = 1.0f; }

    // MPS ansatz on the (unnormalized) state: 2 layers x 3 blocks.
    // Local wire q <-> bit (3-q). Block blk: RY(w[l,blk,0]) on wire blk,
    // RY(w[l,blk,1]) on wire blk+1, CNOT(blk, blk+1).
#pragma unroll
    for (int l = 0; l < 2; ++l) {
#pragma unroll
        for (int blk = 0; blk < 3; ++blk) {
            const int wi = (l * 3 + blk) * 2;
            ry_on(st, 3 - blk, sc[wi],     ss[wi]);
            ry_on(st, 2 - blk, sc[wi + 1], ss[wi + 1]);
            cnot_on(st, 3 - blk, 2 - blk);
        }
    }

    // Swap-test result: P(0) = 0.5*(1 + sum_{cd} psi[0,0,c,d]^2)
    // = indices 0..3 of the flat state; divide by n2 (deferred normalization).
    float num = st[0] * st[0] + st[1] * st[1] + st[2] * st[2] + st[3] * st[3];
    out[idx] = 0.5f * (1.0f + num / n2);
}

extern "C" void kernel_launch(void* const* d_in, const int* in_sizes, int n_in,
                              void* d_out, int out_size, void* d_ws, size_t ws_size,
                              hipStream_t stream) {
    const float* img  = (const float*)d_in[0];
    const float* wmps = (const float*)d_in[1];
    float* out = (float*)d_out;

    const int block = 256;
    const int grid  = (NPATCH + block - 1) / block;  // 961
    encoder_kernel<<<grid, block, 0, stream>>>(img, wmps, out);
}

// Round 2
// 9.827 us; speedup vs baseline: 1.0702x; 1.0702x over previous
//
#include <hip/hip_runtime.h>
#include <math.h>

// Problem constants
#define BS     256
#define IMG_H  64
#define IMG_W  64
#define OH     31
#define OW     31
#define NPOS   (OH * OW)          // 961
#define NPATCH (BS * NPOS)        // 246016 = 961 blocks * 256 threads exactly

// RY(theta) on bit `bit` of a 16-amplitude real state in registers.
__device__ __forceinline__ void ry_on(float* st, int bit, float c, float s) {
    const int m = 1 << bit;
#pragma unroll
    for (int i = 0; i < 16; ++i) {
        if (!(i & m)) {
            float a0 = st[i];
            float a1 = st[i | m];
            st[i]     = c * a0 - s * a1;
            st[i | m] = s * a0 + c * a1;
        }
    }
}

// CNOT control bit cb, target bit tb (pure register rename + swap).
__device__ __forceinline__ void cnot_on(float* st, int cb, int tb) {
    const int cm = 1 << cb, tm = 1 << tb;
#pragma unroll
    for (int i = 0; i < 16; ++i) {
        if ((i & cm) && !(i & tm)) {
            float tmp = st[i];
            st[i] = st[i | tm];
            st[i | tm] = tmp;
        }
    }
}

__global__ __launch_bounds__(256) void encoder_kernel(
    const float* __restrict__ img,     // (256,1,64,64)
    const float* __restrict__ wmps,    // (2,3,2) = 12 floats
    float* __restrict__ out)           // (256,1,961)
{
    __shared__ float sc[12], ss[12];
    const int t = threadIdx.x;
    if (t < 12) {
        float th = 0.5f * wmps[t];
        sc[t] = cosf(th);
        ss[t] = sinf(th);
    }
    __syncthreads();

    const int idx = blockIdx.x * 256 + t;        // grid exactly tiles NPATCH
    const int b   = idx / NPOS;
    const int pos = idx - b * NPOS;
    const int oi  = pos / OW;
    const int oj  = pos - oi * OW;

    // Patch base: row 2*oi, col 2*oj -> even column, 8B-aligned.
    const float2* base2 = (const float2*)(img + ((size_t)b * IMG_H + (size_t)(oi * 2)) * IMG_W)
                          + oj;                  // float2 index = col/2 = oj

    // Load 16-value patch as 8 x float2 (feature order kh*4+kw), track |p|^2.
    float st[16];
    float n2 = 0.0f;
#pragma unroll
    for (int kh = 0; kh < 4; ++kh) {
        float2 lo = base2[kh * (IMG_W / 2)];
        float2 hi = base2[kh * (IMG_W / 2) + 1];
        st[kh * 4 + 0] = lo.x;
        st[kh * 4 + 1] = lo.y;
        st[kh * 4 + 2] = hi.x;
        st[kh * 4 + 3] = hi.y;
        n2 += lo.x * lo.x + lo.y * lo.y + hi.x * hi.x + hi.y * hi.y;
    }

    // norm==0 fallback: reference embeds e0.
    if (n2 <= 0.0f) { st[0] = 1.0f; n2 = 1.0f; }

    // MPS ansatz (unnormalized state): 2 layers x 3 blocks.
    // Local wire q <-> bit (3-q).
#pragma unroll
    for (int l = 0; l < 2; ++l) {
#pragma unroll
        for (int blk = 0; blk < 3; ++blk) {
            const int wi = (l * 3 + blk) * 2;
            ry_on(st, 3 - blk, sc[wi],     ss[wi]);
            ry_on(st, 2 - blk, sc[wi + 1], ss[wi + 1]);
            cnot_on(st, 3 - blk, 2 - blk);
        }
    }

    // P(0) = 0.5*(1 + (sum of first 4 amps^2)/|p|^2); fast rcp is plenty
    // accurate (rel err ~1e-7 vs threshold 1.9e-2).
    float num = st[0] * st[0] + st[1] * st[1] + st[2] * st[2] + st[3] * st[3];
    out[idx] = 0.5f * (1.0f + num * __builtin_amdgcn_rcpf(n2));
}

extern "C" void kernel_launch(void* const* d_in, const int* in_sizes, int n_in,
                              void* d_out, int out_size, void* d_ws, size_t ws_size,
                              hipStream_t stream) {
    const float* img  = (const float*)d_in[0];
    const float* wmps = (const float*)d_in[1];
    float* out = (float*)d_out;

    encoder_kernel<<<NPATCH / 256, 256, 0, stream>>>(img, wmps, out);
}